// Round 2
// baseline (300.349 us; speedup 1.0000x reference)
//
#include <hip/hip_runtime.h>
#include <cstdint>
#include <cstddef>

// Problem constants
constexpr int N = 4096;
constexpr int B = 32;
constexpr int BN = B * N;          // 131072
constexpr size_t NN = (size_t)N * N;  // 16777216

constexpr float ALPHA = 0.025f;
constexpr float BETA = 0.00025f;
constexpr float T_NOW = 10.0f;
constexpr float INV_EXP_TAU = 0.02f;          // 1/50
constexpr float INV_TAU_V = 0.98019867f;      // exp(-1/50)
constexpr float INV_TAU_I = 0.36787944f;      // exp(-1)

// ---------------------------------------------------------------------------
// Pass A: per-neuron spike masks + max_st + rowfac; writes S output.
// ---------------------------------------------------------------------------
__global__ __launch_bounds__(256) void pass_a(
    const float* __restrict__ mem_pot, const float* __restrict__ mem_pot_p,
    const float* __restrict__ st, float* __restrict__ S_out,
    uint32_t* __restrict__ maskS, uint32_t* __restrict__ maskSP,
    float* __restrict__ max_st, float* __restrict__ rowfac) {
  int j = blockIdx.x * blockDim.x + threadIdx.x;
  if (j >= N) return;
  float stj = st[j];
  uint32_t ms = 0u, msp = 0u;
  float maxv = -3.0e38f;
  #pragma unroll
  for (int b = 0; b < B; ++b) {
    float p = mem_pot[b * N + j];
    float pp = mem_pot_p[b * N + j];
    bool s = (p - 1.0f) > 0.0f;
    bool sp = ((pp - 1.0f) - ALPHA) > 0.0f;
    S_out[b * N + j] = s ? 1.0f : 0.0f;
    ms |= (uint32_t)s << b;
    msp |= (uint32_t)sp << b;
    maxv = fmaxf(maxv, s ? T_NOW : stj);
  }
  maskS[j] = ms;
  maskSP[j] = msp;
  max_st[j] = maxv;
  rowfac[j] = msp ? ALPHA : 0.0f;
}

// ---------------------------------------------------------------------------
// Pass B v2: one block per row i. Stage all global loads up front, compute
// W_new[i,:], accumulate SWT[b,i] = sum_j S[b,j]*W_new[i,j], LDS-transpose
// reduce (replaces the 384-op shfl butterfly).
// ---------------------------------------------------------------------------
__global__ __launch_bounds__(256) void pass_b(
    const float* __restrict__ W, const uint32_t* __restrict__ maskS,
    const float* __restrict__ max_st, const float* __restrict__ rowfac,
    float* __restrict__ Wout, float* __restrict__ SWT) {
  int i = blockIdx.x;
  int tid = threadIdx.x;
  float mst_i = max_st[i];
  float fac_i = rowfac[i];

  const float4* __restrict__ Wrow = (const float4*)(W + (size_t)i * N);
  float4* __restrict__ Wo = (float4*)(Wout + (size_t)i * N);
  const float4* __restrict__ mstv = (const float4*)max_st;
  const uint4* __restrict__ mv = (const uint4*)maskS;

  // Stage all 12 global loads first: one waitcnt, then pure VALU.
  float4 w[4], mj[4];
  uint4 m[4];
  #pragma unroll
  for (int it = 0; it < 4; ++it) {
    int idx = it * 256 + tid;
    w[it] = Wrow[idx];
    mj[it] = mstv[idx];
    m[it] = mv[idx];
  }

  float acc[32];
  #pragma unroll
  for (int b = 0; b < 32; ++b) acc[b] = 0.0f;

  auto upd = [&](float ww, float mstj) -> float {
    float d = fabsf(mst_i - mstj);
    float ex = __expf(d * INV_EXP_TAU);
    float u = ww + BETA - fac_i * ex;
    u = fminf(fmaxf(u, 0.0f), 1.0f);
    return (ww > 0.0f) ? u : ww;
  };

  #pragma unroll
  for (int it = 0; it < 4; ++it) {
    int idx = it * 256 + tid;
    float4 wo;
    wo.x = upd(w[it].x, mj[it].x);
    wo.y = upd(w[it].y, mj[it].y);
    wo.z = upd(w[it].z, mj[it].z);
    wo.w = upd(w[it].w, mj[it].w);
    Wo[idx] = wo;
    #pragma unroll
    for (int b = 0; b < 32; ++b) {
      acc[b] = fmaf(wo.x, (float)((m[it].x >> b) & 1u), acc[b]);
      acc[b] = fmaf(wo.y, (float)((m[it].y >> b) & 1u), acc[b]);
      acc[b] = fmaf(wo.z, (float)((m[it].z >> b) & 1u), acc[b]);
      acc[b] = fmaf(wo.w, (float)((m[it].w >> b) & 1u), acc[b]);
    }
  }

  // LDS transpose reduction: 256 threads x 32 partials -> 32 sums.
  __shared__ float red[256][33];   // +1 pad: conflict-free columns
  #pragma unroll
  for (int b = 0; b < 32; ++b) red[tid][b] = acc[b];
  __syncthreads();
  __shared__ float red2[8][32];
  {
    int b = tid & 31, g = tid >> 5;
    float s = 0.0f;
    #pragma unroll
    for (int r = 0; r < 32; ++r) s += red[g * 32 + r][b];
    red2[g][b] = s;
  }
  __syncthreads();
  if (tid < 32) {
    float s = 0.0f;
    #pragma unroll
    for (int g = 0; g < 8; ++g) s += red2[g][tid];
    SWT[tid * N + i] = s;
  }
}

// ---------------------------------------------------------------------------
// Pass C v2: SW[b,j] = sum_k S[b,k] * W_new[k,j].
// Block = 256 threads = 64 col-groups (float4) x 4 batch-groups (8 batches).
// Grid = (16 col tiles of 256 cols) x (64 row strips of 64 rows) = 1024 blocks.
// maskS[k] is wave-uniform -> scalar branch skips non-spiking (b,k) pairs.
// ---------------------------------------------------------------------------
__global__ __launch_bounds__(256) void pass_c(
    const float* __restrict__ Wn, const uint32_t* __restrict__ maskS,
    float* __restrict__ SW) {
  int tid = threadIdx.x;
  int cg = tid & 63;        // float4 column group within tile
  int bg = tid >> 6;        // batch group: batches [bg*8, bg*8+8)
  int j4 = blockIdx.x * 64 + cg;
  int k0 = blockIdx.y * 64;
  const float4* __restrict__ W4 = (const float4*)Wn;

  float acc[8][4];
  #pragma unroll
  for (int b = 0; b < 8; ++b)
    #pragma unroll
    for (int c = 0; c < 4; ++c) acc[b][c] = 0.0f;

  #pragma unroll 4
  for (int kk = 0; kk < 64; ++kk) {
    int k = k0 + kk;
    float4 w = W4[(size_t)k * (N / 4) + j4];
    uint32_t m = maskS[k] >> (bg * 8);   // wave-uniform
    #pragma unroll
    for (int b = 0; b < 8; ++b) {
      if (m & (1u << b)) {   // uniform branch: skipped ~84% of the time
        acc[b][0] += w.x;
        acc[b][1] += w.y;
        acc[b][2] += w.z;
        acc[b][3] += w.w;
      }
    }
  }

  int j = j4 * 4;
  #pragma unroll
  for (int b = 0; b < 8; ++b) {
    float* dst = &SW[(size_t)(bg * 8 + b) * N + j];
    atomicAdd(dst + 0, acc[b][0]);
    atomicAdd(dst + 1, acc[b][1]);
    atomicAdd(dst + 2, acc[b][2]);
    atomicAdd(dst + 3, acc[b][3]);
  }
}

// ---------------------------------------------------------------------------
// Pass D: integrate + leak + reset + refractory.
// ---------------------------------------------------------------------------
__global__ __launch_bounds__(256) void pass_d(
    const float* __restrict__ inp, const float* __restrict__ mem_pot,
    const float* __restrict__ mem_cur, const float* __restrict__ mem_pot_p,
    const float* __restrict__ mem_cur_p, const int* __restrict__ refrac_in,
    const uint32_t* __restrict__ maskS, const uint32_t* __restrict__ maskSP,
    float* __restrict__ pot_out, float* __restrict__ cur_out,
    float* __restrict__ potp_out, float* __restrict__ curp_out,
    float* __restrict__ refrac_out) {
  int e = blockIdx.x * 256 + threadIdx.x;
  int b = e >> 12;
  int j = e & (N - 1);
  int r = refrac_in[e];
  int rd = (r > 0) ? (r - 1) : r;
  bool active = (rd == 0);
  bool s = (maskS[j] >> b) & 1u;
  bool sp = (maskSP[j] >> b) & 1u;
  float SW = cur_out[e];
  float SWT = potp_out[e];
  float cur = mem_cur[e], pot = mem_pot[e];
  float curp = mem_cur_p[e], potp = mem_pot_p[e];

  float cur_n = active ? (inp[e] + SW + cur) : cur;
  float curp_n = active ? (SWT + curp) : curp;
  float pot_n = active ? (cur_n + pot) : pot;
  float potp_n = active ? (curp_n + potp) : potp;

  pot_n *= INV_TAU_V;
  cur_n *= INV_TAU_I;
  potp_n *= INV_TAU_V;
  curp_n *= INV_TAU_I;

  if (s) pot_n = 0.0f;
  if (sp) potp_n = 0.0f;
  int rn = s ? 2 : rd;

  pot_out[e] = pot_n;
  cur_out[e] = cur_n;
  potp_out[e] = potp_n;
  curp_out[e] = curp_n;
  refrac_out[e] = (float)rn;
}

// ---------------------------------------------------------------------------
extern "C" void kernel_launch(void* const* d_in, const int* in_sizes, int n_in,
                              void* d_out, int out_size, void* d_ws, size_t ws_size,
                              hipStream_t stream) {
  const float* inp = (const float*)d_in[0];
  const float* W = (const float*)d_in[1];
  const float* mem_pot = (const float*)d_in[2];
  const float* mem_cur = (const float*)d_in[3];
  const float* mem_pot_p = (const float*)d_in[4];
  const float* mem_cur_p = (const float*)d_in[5];
  const float* st = (const float*)d_in[6];
  const int* refrac = (const int*)d_in[7];

  float* out = (float*)d_out;
  float* S_out = out;
  float* pot_out = out + BN;
  float* W_out = out + 2 * (size_t)BN;
  float* cur_out = W_out + NN;
  float* potp_out = cur_out + BN;
  float* curp_out = potp_out + BN;
  float* refrac_out = curp_out + BN;

  uint32_t* maskS = (uint32_t*)d_ws;
  uint32_t* maskSP = maskS + N;
  float* max_st = (float*)(maskSP + N);
  float* rowfac = max_st + N;

  hipMemsetAsync(cur_out, 0, (size_t)BN * sizeof(float), stream);

  pass_a<<<N / 256, 256, 0, stream>>>(mem_pot, mem_pot_p, st, S_out, maskS,
                                      maskSP, max_st, rowfac);
  pass_b<<<N, 256, 0, stream>>>(W, maskS, max_st, rowfac, W_out, potp_out);
  pass_c<<<dim3(16, 64), 256, 0, stream>>>(W_out, maskS, cur_out);
  pass_d<<<BN / 256, 256, 0, stream>>>(inp, mem_pot, mem_cur, mem_pot_p,
                                       mem_cur_p, refrac, maskS, maskSP,
                                       pot_out, cur_out, potp_out, curp_out,
                                       refrac_out);
}

// Round 3
// 166.814 us; speedup vs baseline: 1.8005x; 1.8005x over previous
//
#include <hip/hip_runtime.h>
#include <cstdint>
#include <cstddef>

// Problem constants
constexpr int N = 4096;
constexpr int B = 32;
constexpr int BN = B * N;             // 131072
constexpr size_t NN = (size_t)N * N;  // 16777216
constexpr int KCHUNKS = 4;            // K-split for the MFMA pass
constexpr int KC = N / KCHUNKS;       // 1024

constexpr float ALPHA = 0.025f;
constexpr float BETA = 0.00025f;
constexpr float T_NOW = 10.0f;
constexpr float INV_EXP_TAU = 0.02f;          // 1/50
constexpr float INV_TAU_V = 0.98019867f;      // exp(-1/50)
constexpr float INV_TAU_I = 0.36787944f;      // exp(-1)

typedef __attribute__((ext_vector_type(8))) short short8;
typedef __attribute__((ext_vector_type(4))) float f32x4;

__device__ inline unsigned short f2bf(float f) {
  uint32_t u = __float_as_uint(f);
  u += 0x7FFFu + ((u >> 16) & 1u);   // RNE
  return (unsigned short)(u >> 16);
}

// ---------------------------------------------------------------------------
// Pass A: per-neuron spike masks + max_st + rowfac; writes S (f32) and S_bf
// (bf16 copy, the MFMA A-matrix).
// ---------------------------------------------------------------------------
__global__ __launch_bounds__(256) void pass_a(
    const float* __restrict__ mem_pot, const float* __restrict__ mem_pot_p,
    const float* __restrict__ st, float* __restrict__ S_out,
    unsigned short* __restrict__ S_bf,
    uint32_t* __restrict__ maskS, uint32_t* __restrict__ maskSP,
    float* __restrict__ max_st, float* __restrict__ rowfac) {
  int j = blockIdx.x * blockDim.x + threadIdx.x;
  if (j >= N) return;
  float stj = st[j];
  uint32_t ms = 0u, msp = 0u;
  float maxv = -3.0e38f;
  #pragma unroll
  for (int b = 0; b < B; ++b) {
    float p = mem_pot[b * N + j];
    float pp = mem_pot_p[b * N + j];
    bool s = (p - 1.0f) > 0.0f;
    bool sp = ((pp - 1.0f) - ALPHA) > 0.0f;
    S_out[b * N + j] = s ? 1.0f : 0.0f;
    S_bf[b * N + j] = s ? 0x3F80u : 0u;   // bf16 1.0 / 0.0
    ms |= (uint32_t)s << b;
    msp |= (uint32_t)sp << b;
    maxv = fmaxf(maxv, s ? T_NOW : stj);
  }
  maskS[j] = ms;
  maskSP[j] = msp;
  max_st[j] = maxv;
  rowfac[j] = msp ? ALPHA : 0.0f;
}

// ---------------------------------------------------------------------------
// Pass B: pure streaming W-update. One block per row i.
// ---------------------------------------------------------------------------
__global__ __launch_bounds__(256) void pass_b(
    const float* __restrict__ W, const float* __restrict__ max_st,
    const float* __restrict__ rowfac, float* __restrict__ Wout) {
  int i = blockIdx.x;
  int tid = threadIdx.x;
  float mst_i = max_st[i];
  float fac_i = rowfac[i];

  const float4* __restrict__ Wrow = (const float4*)(W + (size_t)i * N);
  float4* __restrict__ Wo = (float4*)(Wout + (size_t)i * N);
  const float4* __restrict__ mstv = (const float4*)max_st;

  float4 w[4], mj[4];
  #pragma unroll
  for (int it = 0; it < 4; ++it) {
    int idx = it * 256 + tid;
    w[it] = Wrow[idx];
    mj[it] = mstv[idx];
  }

  auto upd = [&](float ww, float mstj) -> float {
    float d = fabsf(mst_i - mstj);
    float ex = __expf(d * INV_EXP_TAU);
    float u = ww + BETA - fac_i * ex;
    u = fminf(fmaxf(u, 0.0f), 1.0f);
    return (ww > 0.0f) ? u : ww;
  };

  #pragma unroll
  for (int it = 0; it < 4; ++it) {
    int idx = it * 256 + tid;
    float4 wo;
    wo.x = upd(w[it].x, mj[it].x);
    wo.y = upd(w[it].y, mj[it].y);
    wo.z = upd(w[it].z, mj[it].z);
    wo.w = upd(w[it].w, mj[it].w);
    Wo[idx] = wo;
  }
}

// ---------------------------------------------------------------------------
// Pass MFMA: both skinny GEMMs via mfma_f32_16x16x32_bf16.
//   gemm 0 (blockIdx.z==0): SW[b,j]  = sum_k S[b,k]*Wn[k,j]
//   gemm 1 (blockIdx.z==1): SWT[b,i] = sum_j S[b,j]*Wn[i,j]
// Verified layouts (guide §3 / attention note):
//   A[m=lane&15][k=quad*8+i], B[k=quad*8+i][n=lane&15],
//   C/D: col=lane&15, row=quad*4+reg.
// K split into KCHUNKS non-atomic partial buffers, reduced in pass_d.
// Block = 4 waves; wave -> one 16-wide n-tile.
// ---------------------------------------------------------------------------
__global__ __launch_bounds__(256) void pass_mfma(
    const float* __restrict__ Wn, const unsigned short* __restrict__ S_bf,
    float* __restrict__ partSW, float* __restrict__ partSWT) {
  int wv = threadIdx.x >> 6;
  int lane = threadIdx.x & 63;
  int ntile = blockIdx.x * 4 + wv;     // 0..255
  int j0 = ntile * 16;
  int kchunk = blockIdx.y;             // 0..KCHUNKS-1
  int kbase = kchunk * KC;
  int gemm = blockIdx.z;
  int quad = lane >> 4;
  int nl = lane & 15;

  f32x4 acc0 = {0.f, 0.f, 0.f, 0.f};
  f32x4 acc1 = {0.f, 0.f, 0.f, 0.f};
  const unsigned short* A0p = S_bf + (size_t)nl * N;          // batches 0-15
  const unsigned short* A1p = S_bf + (size_t)(nl + 16) * N;   // batches 16-31

  if (gemm == 0) {
    #pragma unroll 4
    for (int it = 0; it < KC / 32; ++it) {
      int k0 = kbase + it * 32;
      short8 a0 = *(const short8*)(A0p + k0 + quad * 8);
      short8 a1 = *(const short8*)(A1p + k0 + quad * 8);
      short8 bf;
      #pragma unroll
      for (int i = 0; i < 8; ++i) {
        float f = Wn[(size_t)(k0 + quad * 8 + i) * N + j0 + nl];
        bf[i] = (short)f2bf(f);
      }
      acc0 = __builtin_amdgcn_mfma_f32_16x16x32_bf16(a0, bf, acc0, 0, 0, 0);
      acc1 = __builtin_amdgcn_mfma_f32_16x16x32_bf16(a1, bf, acc1, 0, 0, 0);
    }
  } else {
    const float4* __restrict__ Wr =
        (const float4*)(Wn + (size_t)(j0 + nl) * N);  // row i = j0+nl of Wn
    #pragma unroll 4
    for (int it = 0; it < KC / 32; ++it) {
      int k0 = kbase + it * 32;
      short8 a0 = *(const short8*)(A0p + k0 + quad * 8);
      short8 a1 = *(const short8*)(A1p + k0 + quad * 8);
      int f4 = (k0 + quad * 8) >> 2;
      float4 f0 = Wr[f4];
      float4 f1 = Wr[f4 + 1];
      short8 bf;
      bf[0] = (short)f2bf(f0.x); bf[1] = (short)f2bf(f0.y);
      bf[2] = (short)f2bf(f0.z); bf[3] = (short)f2bf(f0.w);
      bf[4] = (short)f2bf(f1.x); bf[5] = (short)f2bf(f1.y);
      bf[6] = (short)f2bf(f1.z); bf[7] = (short)f2bf(f1.w);
      acc0 = __builtin_amdgcn_mfma_f32_16x16x32_bf16(a0, bf, acc0, 0, 0, 0);
      acc1 = __builtin_amdgcn_mfma_f32_16x16x32_bf16(a1, bf, acc1, 0, 0, 0);
    }
  }

  float* part = (gemm == 0) ? partSW : partSWT;
  size_t base = (size_t)kchunk * BN + j0 + nl;
  #pragma unroll
  for (int r = 0; r < 4; ++r) {
    part[base + (size_t)(quad * 4 + r) * N] = acc0[r];
    part[base + (size_t)(16 + quad * 4 + r) * N] = acc1[r];
  }
}

// ---------------------------------------------------------------------------
// Pass D: reduce K-partials, integrate + leak + reset + refractory.
// ---------------------------------------------------------------------------
__global__ __launch_bounds__(256) void pass_d(
    const float* __restrict__ inp, const float* __restrict__ mem_pot,
    const float* __restrict__ mem_cur, const float* __restrict__ mem_pot_p,
    const float* __restrict__ mem_cur_p, const int* __restrict__ refrac_in,
    const uint32_t* __restrict__ maskS, const uint32_t* __restrict__ maskSP,
    const float* __restrict__ partSW, const float* __restrict__ partSWT,
    float* __restrict__ pot_out, float* __restrict__ cur_out,
    float* __restrict__ potp_out, float* __restrict__ curp_out,
    float* __restrict__ refrac_out) {
  int e = blockIdx.x * 256 + threadIdx.x;
  int b = e >> 12;
  int j = e & (N - 1);

  float SW = 0.0f, SWT = 0.0f;
  #pragma unroll
  for (int c = 0; c < KCHUNKS; ++c) {
    SW += partSW[(size_t)c * BN + e];
    SWT += partSWT[(size_t)c * BN + e];
  }

  int r = refrac_in[e];
  int rd = (r > 0) ? (r - 1) : r;
  bool active = (rd == 0);
  bool s = (maskS[j] >> b) & 1u;
  bool sp = (maskSP[j] >> b) & 1u;
  float cur = mem_cur[e], pot = mem_pot[e];
  float curp = mem_cur_p[e], potp = mem_pot_p[e];

  float cur_n = active ? (inp[e] + SW + cur) : cur;
  float curp_n = active ? (SWT + curp) : curp;
  float pot_n = active ? (cur_n + pot) : pot;
  float potp_n = active ? (curp_n + potp) : potp;

  pot_n *= INV_TAU_V;
  cur_n *= INV_TAU_I;
  potp_n *= INV_TAU_V;
  curp_n *= INV_TAU_I;

  if (s) pot_n = 0.0f;
  if (sp) potp_n = 0.0f;
  int rn = s ? 2 : rd;

  pot_out[e] = pot_n;
  cur_out[e] = cur_n;
  potp_out[e] = potp_n;
  curp_out[e] = curp_n;
  refrac_out[e] = (float)rn;
}

// ---------------------------------------------------------------------------
extern "C" void kernel_launch(void* const* d_in, const int* in_sizes, int n_in,
                              void* d_out, int out_size, void* d_ws, size_t ws_size,
                              hipStream_t stream) {
  const float* inp = (const float*)d_in[0];
  const float* W = (const float*)d_in[1];
  const float* mem_pot = (const float*)d_in[2];
  const float* mem_cur = (const float*)d_in[3];
  const float* mem_pot_p = (const float*)d_in[4];
  const float* mem_cur_p = (const float*)d_in[5];
  const float* st = (const float*)d_in[6];
  const int* refrac = (const int*)d_in[7];

  float* out = (float*)d_out;
  float* S_out = out;
  float* pot_out = out + BN;
  float* W_out = out + 2 * (size_t)BN;
  float* cur_out = W_out + NN;
  float* potp_out = cur_out + BN;
  float* curp_out = potp_out + BN;
  float* refrac_out = curp_out + BN;

  // Workspace layout (all 16B-aligned): ~4.6 MB total
  uint32_t* maskS = (uint32_t*)d_ws;                      // 16 KB
  uint32_t* maskSP = maskS + N;                           // 16 KB
  float* max_st = (float*)(maskSP + N);                   // 16 KB
  float* rowfac = max_st + N;                             // 16 KB
  unsigned short* S_bf = (unsigned short*)(rowfac + N);   // 256 KB
  float* partSW = (float*)(S_bf + BN);                    // KCHUNKS*BN*4 = 2 MB
  float* partSWT = partSW + (size_t)KCHUNKS * BN;         // 2 MB

  pass_a<<<N / 256, 256, 0, stream>>>(mem_pot, mem_pot_p, st, S_out, S_bf,
                                      maskS, maskSP, max_st, rowfac);
  pass_b<<<N, 256, 0, stream>>>(W, max_st, rowfac, W_out);
  pass_mfma<<<dim3(64, KCHUNKS, 2), 256, 0, stream>>>(W_out, S_bf, partSW,
                                                      partSWT);
  pass_d<<<BN / 256, 256, 0, stream>>>(inp, mem_pot, mem_cur, mem_pot_p,
                                       mem_cur_p, refrac, maskS, maskSP,
                                       partSW, partSWT, pot_out, cur_out,
                                       potp_out, curp_out, refrac_out);
}